// Round 14
// baseline (2181.300 us; speedup 1.0000x reference)
//
#include <hip/hip_runtime.h>
#include <math.h>

// Problem constants
#define BTOT   4096
#define CIN    3
#define TIN    64
#define SIN    128

// ws layout (float offsets)
#define SEQ_OFF    0                            // [4096][60][124]
#define G_OFF      (SEQ_OFF + 4096*60*124)      // [4096][129]
#define HST_OFF    (G_OFF + 4096*129)           // [4096][148] h state between chunks
#define WHH144_OFF (HST_OFF + 4096*148)         // [387][144] padded Whh
#define WIH128_OFF (WHH144_OFF + 387*144)       // [387][128] padded Wih
#define MUWP_OFF   (WIH128_OFF + 387*128)       // [129][260]
#define LSWP_OFF   (MUWP_OFF + 129*260)         // [129][260]
#define GIC_OFF    (LSWP_OFF + 129*260)         // [CT][387][4096] gi chunk

// Inline transcendentals (no libm calls in hot loops; ocml calls force
// loop-resident values into callee-saved regs -> spill)
__device__ __forceinline__ float fast_tanh(float x) {
    float ax = fabsf(x);
    float t  = __expf(-2.f * ax);
    float r  = (1.f - t) / (1.f + t);
    return copysignf(r, x);
}
__device__ __forceinline__ float fast_sigmoid(float x) {
    return 1.f / (1.f + __expf(-x));
}

// R13 lesson: named-scalar weights became SSA but the allocator REMATERIALIZED
// the loop-invariant loads (VGPR=84 < 108 needed) -> 27 scattered global loads
// per step. asm-pinning makes remat illegal: the value must stay in VGPRs.
#define PIN4(v_) asm volatile("" : "+v"((v_).x), "+v"((v_).y), "+v"((v_).z), "+v"((v_).w));

// ---------------------------------------------------------------------------
// Prep: pad Whh rows 129->144, Wih rows 124->128, fc weights rows 258->260
// ---------------------------------------------------------------------------
__global__ __launch_bounds__(256) void prep_pad(
    const float* __restrict__ Whh, const float* __restrict__ Wih,
    const float* __restrict__ muw, const float* __restrict__ lsw,
    float* __restrict__ ws)
{
    int idx = blockIdx.x * 256 + threadIdx.x;
    const int N1 = 387 * 144;
    const int N0 = 387 * 128;
    const int N2 = 129 * 260;
    if (idx < N1) {
        int n = idx / 144, k = idx - n * 144;
        ws[WHH144_OFF + idx] = (k < 129) ? Whh[n * 129 + k] : 0.f;
    } else if (idx < N1 + N0) {
        int i = idx - N1; int n = i >> 7, k = i & 127;
        ws[WIH128_OFF + i] = (k < 124) ? Wih[n * 124 + k] : 0.f;
    } else if (idx < N1 + N0 + N2) {
        int i = idx - N1 - N0; int j = i / 260, k = i - j * 260;
        ws[MUWP_OFF + i] = (k < 258) ? muw[j * 258 + k] : 0.f;
    } else if (idx < N1 + N0 + 2 * N2) {
        int i = idx - N1 - N0 - N2; int j = i / 260, k = i - j * 260;
        ws[LSWP_OFF + i] = (k < 258) ? lsw[j * 258 + k] : 0.f;
    }
}

// ---------------------------------------------------------------------------
// Fused conv1+conv2 v2 (register-blocked, weight-resident) — passing R13.
// ---------------------------------------------------------------------------
#define C1SEG(c_, kt_, W0_, W1_, W2_) { \
    const float* rp_ = xt + ((c_) * 14 + tq + (kt_)) * 128 + s0; \
    float4 v4_ = *(const float4*)rp_; \
    float2 v2_ = *(const float2*)(rp_ + 4); \
    acc0 += v4_.x*(W0_) + v4_.y*(W1_) + v4_.z*(W2_); \
    acc1 += v4_.y*(W0_) + v4_.z*(W1_) + v4_.w*(W2_); \
    acc2 += v4_.z*(W0_) + v4_.w*(W1_) + v2_.x*(W2_); \
    acc3 += v4_.w*(W0_) + v2_.x*(W1_) + v2_.y*(W2_); }

#define C2SEG(o_, kt_, W0_, W1_, W2_) { \
    const float* rp_ = h1t + ((o_) * 12 + tq + (kt_)) * 128 + s0; \
    float4 v4_ = *(const float4*)rp_; \
    float2 v2_ = *(const float2*)(rp_ + 4); \
    acc0 += v4_.x*(W0_) + v4_.y*(W1_) + v4_.z*(W2_); \
    acc1 += v4_.y*(W0_) + v4_.z*(W1_) + v4_.w*(W2_); \
    acc2 += v4_.z*(W0_) + v4_.w*(W1_) + v2_.x*(W2_); \
    acc3 += v4_.w*(W0_) + v2_.x*(W1_) + v2_.y*(W2_); }

__global__ __launch_bounds__(256) void conv_fused(
    const float* __restrict__ x,
    const float* __restrict__ w1, const float* __restrict__ b1,
    const float* __restrict__ w2, const float* __restrict__ b2,
    float* __restrict__ seq)
{
    __shared__ __attribute__((aligned(16))) float xt[3 * 14 * 128 + 8];
    __shared__ __attribute__((aligned(16))) float h1t[6 * 12 * 128];
    __shared__ float w1s[162];
    __shared__ float w2s[54];
    __shared__ float b1s[6];
    __shared__ float b2s;

    const int tid  = threadIdx.x;
    const int tile = blockIdx.x;   // 0..5
    const int bb   = blockIdx.y;   // batch
    const int T0   = tile * 10;

    if (tid < 162)                  w1s[tid] = w1[tid];
    if (tid >= 192 && tid < 246)    w2s[tid - 192] = w2[tid - 192];
    if (tid >= 248 && tid < 254)    b1s[tid - 248] = b1[tid - 248];
    if (tid == 255)                 b2s = b2[0];

    // stage x tile: 42 rows x 32 float4 (coalesced)
    {
        const float* xb = x + (size_t)bb * CIN * TIN * SIN;
        for (int i = tid; i < 3 * 14 * 32; i += 256) {
            int c   = i / (14 * 32);
            int rem = i - c * (14 * 32);
            int t   = rem >> 5;
            int k4  = rem & 31;
            ((float4*)(xt + (c * 14 + t) * 128))[k4] =
                *(const float4*)(xb + ((size_t)(c * TIN + T0 + t)) * SIN + k4 * 4);
        }
    }
    __syncthreads();

    // ---- conv1 + leaky: tid<192, thread = (o, 4-col group), 12 t-rows ----
    if (tid < 192) {
        const int o  = tid >> 5;
        const int s0 = (tid & 31) * 4;
        const float* wb = w1s + o * 27;
        float w000 = wb[0],  w001 = wb[1],  w002 = wb[2];
        float w010 = wb[3],  w011 = wb[4],  w012 = wb[5];
        float w020 = wb[6],  w021 = wb[7],  w022 = wb[8];
        float w100 = wb[9],  w101 = wb[10], w102 = wb[11];
        float w110 = wb[12], w111 = wb[13], w112 = wb[14];
        float w120 = wb[15], w121 = wb[16], w122 = wb[17];
        float w200 = wb[18], w201 = wb[19], w202 = wb[20];
        float w210 = wb[21], w211 = wb[22], w212 = wb[23];
        float w220 = wb[24], w221 = wb[25], w222 = wb[26];
        float bo = b1s[o];
        for (int tq = 0; tq < 12; ++tq) {
            float acc0 = bo, acc1 = bo, acc2 = bo, acc3 = bo;
            C1SEG(0, 0, w000, w001, w002)
            C1SEG(0, 1, w010, w011, w012)
            C1SEG(0, 2, w020, w021, w022)
            C1SEG(1, 0, w100, w101, w102)
            C1SEG(1, 1, w110, w111, w112)
            C1SEG(1, 2, w120, w121, w122)
            C1SEG(2, 0, w200, w201, w202)
            C1SEG(2, 1, w210, w211, w212)
            C1SEG(2, 2, w220, w221, w222)
            float4 r;
            r.x = (acc0 >= 0.f) ? acc0 : 0.01f * acc0;
            r.y = (acc1 >= 0.f) ? acc1 : 0.01f * acc1;
            r.z = (acc2 >= 0.f) ? acc2 : 0.01f * acc2;
            r.w = (acc3 >= 0.f) ? acc3 : 0.01f * acc3;
            *(float4*)(h1t + (o * 12 + tq) * 128 + s0) = r;
        }
    }
    __syncthreads();

    // ---- conv2 + leaky: 310 tasks = (t in [0,10), sg in [0,31)) ----
    {
        float u000 = w2s[0],  u001 = w2s[1],  u002 = w2s[2];
        float u010 = w2s[3],  u011 = w2s[4],  u012 = w2s[5];
        float u020 = w2s[6],  u021 = w2s[7],  u022 = w2s[8];
        float u100 = w2s[9],  u101 = w2s[10], u102 = w2s[11];
        float u110 = w2s[12], u111 = w2s[13], u112 = w2s[14];
        float u120 = w2s[15], u121 = w2s[16], u122 = w2s[17];
        float u200 = w2s[18], u201 = w2s[19], u202 = w2s[20];
        float u210 = w2s[21], u211 = w2s[22], u212 = w2s[23];
        float u220 = w2s[24], u221 = w2s[25], u222 = w2s[26];
        float u300 = w2s[27], u301 = w2s[28], u302 = w2s[29];
        float u310 = w2s[30], u311 = w2s[31], u312 = w2s[32];
        float u320 = w2s[33], u321 = w2s[34], u322 = w2s[35];
        float u400 = w2s[36], u401 = w2s[37], u402 = w2s[38];
        float u410 = w2s[39], u411 = w2s[40], u412 = w2s[41];
        float u420 = w2s[42], u421 = w2s[43], u422 = w2s[44];
        float u500 = w2s[45], u501 = w2s[46], u502 = w2s[47];
        float u510 = w2s[48], u511 = w2s[49], u512 = w2s[50];
        float u520 = w2s[51], u521 = w2s[52], u522 = w2s[53];
        float bo2 = b2s;
        for (int idx = tid; idx < 310; idx += 256) {
            const int tq = idx / 31;
            const int s0 = (idx - tq * 31) * 4;
            float acc0 = bo2, acc1 = bo2, acc2 = bo2, acc3 = bo2;
            C2SEG(0, 0, u000, u001, u002)
            C2SEG(0, 1, u010, u011, u012)
            C2SEG(0, 2, u020, u021, u022)
            C2SEG(1, 0, u100, u101, u102)
            C2SEG(1, 1, u110, u111, u112)
            C2SEG(1, 2, u120, u121, u122)
            C2SEG(2, 0, u200, u201, u202)
            C2SEG(2, 1, u210, u211, u212)
            C2SEG(2, 2, u220, u221, u222)
            C2SEG(3, 0, u300, u301, u302)
            C2SEG(3, 1, u310, u311, u312)
            C2SEG(3, 2, u320, u321, u322)
            C2SEG(4, 0, u400, u401, u402)
            C2SEG(4, 1, u410, u411, u412)
            C2SEG(4, 2, u420, u421, u422)
            C2SEG(5, 0, u500, u501, u502)
            C2SEG(5, 1, u510, u511, u512)
            C2SEG(5, 2, u520, u521, u522)
            float4 r;
            r.x = (acc0 >= 0.f) ? acc0 : 0.01f * acc0;
            r.y = (acc1 >= 0.f) ? acc1 : 0.01f * acc1;
            r.z = (acc2 >= 0.f) ? acc2 : 0.01f * acc2;
            r.w = (acc3 >= 0.f) ? acc3 : 0.01f * acc3;
            *(float4*)(seq + ((size_t)bb * 60 + T0 + tq) * 124 + s0) = r;
        }
    }
}

// ---------------------------------------------------------------------------
// Shared macro kit (R10 lesson: macro params must not be named x/y/z/w)
// ---------------------------------------------------------------------------
#define D4(acc_, hv4_, wv4_) acc_ += (hv4_).x*(wv4_).x + (hv4_).y*(wv4_).y + (hv4_).z*(wv4_).z + (hv4_).w*(wv4_).w;
#define RED(acc_) { acc_ += __shfl_xor(acc_, 1, 64); acc_ += __shfl_xor(acc_, 2, 64); }

// ---------------------------------------------------------------------------
// gi GEMM v2 (weight-resident + asm-pinned): 256 blocks x 576 threads.
// ---------------------------------------------------------------------------
#define GI_ROW(R, aA, aB, aC) { \
    const float4* hv_ = (const float4*)(xs2 + (R) * 132) + kqo8; \
    float4 h4_; \
    h4_ = hv_[0]; D4(aA, h4_, Va0) D4(aB, h4_, Vb0) D4(aC, h4_, Vc0) \
    h4_ = hv_[1]; D4(aA, h4_, Va1) D4(aB, h4_, Vb1) D4(aC, h4_, Vc1) \
    h4_ = hv_[2]; D4(aA, h4_, Va2) D4(aB, h4_, Vb2) D4(aC, h4_, Vc2) \
    h4_ = hv_[3]; D4(aA, h4_, Va3) D4(aB, h4_, Vb3) D4(aC, h4_, Vc3) \
    h4_ = hv_[4]; D4(aA, h4_, Va4) D4(aB, h4_, Vb4) D4(aC, h4_, Vc4) \
    h4_ = hv_[5]; D4(aA, h4_, Va5) D4(aB, h4_, Vb5) D4(aC, h4_, Vc5) \
    h4_ = hv_[6]; D4(aA, h4_, Va6) D4(aB, h4_, Vb6) D4(aC, h4_, Vc6) \
    h4_ = hv_[7]; D4(aA, h4_, Va7) D4(aB, h4_, Vb7) D4(aC, h4_, Vc7) }

#define GI_CHUNK(R0) { \
    float aA0 = 0.f, aB0 = 0.f, aC0 = 0.f, aA1 = 0.f, aB1 = 0.f, aC1 = 0.f; \
    float aA2 = 0.f, aB2 = 0.f, aC2 = 0.f, aA3 = 0.f, aB3 = 0.f, aC3 = 0.f; \
    GI_ROW((R0) + 0, aA0, aB0, aC0) \
    GI_ROW((R0) + 1, aA1, aB1, aC1) \
    GI_ROW((R0) + 2, aA2, aB2, aC2) \
    GI_ROW((R0) + 3, aA3, aB3, aC3) \
    RED(aA0) RED(aB0) RED(aC0) RED(aA1) RED(aB1) RED(aC1) \
    RED(aA2) RED(aB2) RED(aC2) RED(aA3) RED(aB3) RED(aC3) \
    float sA = (kq == 0) ? aA0 : (kq == 1) ? aA1 : (kq == 2) ? aA2 : aA3; \
    float sB = (kq == 0) ? aB0 : (kq == 1) ? aB1 : (kq == 2) ? aB2 : aB3; \
    float sC = (kq == 0) ? aC0 : (kq == 1) ? aC1 : (kq == 2) ? aC2 : aC3; \
    int rw_ = (R0) + kq; \
    GIb[rw_ * 389 + gq]       = sA; \
    GIb[rw_ * 389 + 129 + gq] = sB; \
    GIb[rw_ * 389 + 258 + gq] = sC; }

__global__ __launch_bounds__(576, 3)
__attribute__((amdgpu_waves_per_eu(3, 3)))
void gi_gemm2(
    const float* __restrict__ seq, const float* __restrict__ wih,  // [387][128]
    float* __restrict__ gic, int t0, int nt)
{
    __shared__ __attribute__((aligned(16))) float xs2[16 * 132];  // stride 132
    __shared__ float GIb[16 * 389];

    const int tid    = threadIdx.x;
    const int kq     = tid & 3;
    const int kqo8   = kq * 8;           // f4 offset into a 32-float k-chunk
    const int b0     = blockIdx.x * 16;
    const bool isMain = (tid < 512);
    const int gq     = isMain ? (tid >> 2) : 0;      // [0,128)
    const int rsp    = (tid - 512) >> 2;             // special wave batch row

    const float* wiA;
    const float* wiB;
    const float* wiC;
    if (isMain) {
        wiA = wih + (size_t)gq * 128 + kq * 32;
        wiB = wih + (size_t)(129 + gq) * 128 + kq * 32;
        wiC = wih + (size_t)(258 + gq) * 128 + kq * 32;
    } else {
        wiA = wih + (size_t)128 * 128 + kq * 32;
        wiB = wih + (size_t)257 * 128 + kq * 32;
        wiC = wih + (size_t)386 * 128 + kq * 32;
    }
    float4 Va0 = ((const float4*)wiA)[0], Va1 = ((const float4*)wiA)[1],
           Va2 = ((const float4*)wiA)[2], Va3 = ((const float4*)wiA)[3],
           Va4 = ((const float4*)wiA)[4], Va5 = ((const float4*)wiA)[5],
           Va6 = ((const float4*)wiA)[6], Va7 = ((const float4*)wiA)[7];
    float4 Vb0 = ((const float4*)wiB)[0], Vb1 = ((const float4*)wiB)[1],
           Vb2 = ((const float4*)wiB)[2], Vb3 = ((const float4*)wiB)[3],
           Vb4 = ((const float4*)wiB)[4], Vb5 = ((const float4*)wiB)[5],
           Vb6 = ((const float4*)wiB)[6], Vb7 = ((const float4*)wiB)[7];
    float4 Vc0 = ((const float4*)wiC)[0], Vc1 = ((const float4*)wiC)[1],
           Vc2 = ((const float4*)wiC)[2], Vc3 = ((const float4*)wiC)[3],
           Vc4 = ((const float4*)wiC)[4], Vc5 = ((const float4*)wiC)[5],
           Vc6 = ((const float4*)wiC)[6], Vc7 = ((const float4*)wiC)[7];
    PIN4(Va0) PIN4(Va1) PIN4(Va2) PIN4(Va3) PIN4(Va4) PIN4(Va5) PIN4(Va6) PIN4(Va7)
    PIN4(Vb0) PIN4(Vb1) PIN4(Vb2) PIN4(Vb3) PIN4(Vb4) PIN4(Vb5) PIN4(Vb6) PIN4(Vb7)
    PIN4(Vc0) PIN4(Vc1) PIN4(Vc2) PIN4(Vc3) PIN4(Vc4) PIN4(Vc5) PIN4(Vc6) PIN4(Vc7)

    // zero the k-pad (floats 124..127 of each row) so 0-weight x pad = 0
    if (tid < 64) xs2[(tid >> 2) * 132 + 124 + (tid & 3)] = 0.f;

    const int sr = tid / 31;             // row 0..15 (tid<496)
    const int sk = tid - sr * 31;        // f4 0..30

    for (int tt = 0; tt < nt; ++tt) {
        if (tid < 496) {
            const float4* srcf4 =
                (const float4*)(seq + ((size_t)(b0 + sr) * 60 + (t0 + tt)) * 124);
            ((float4*)(xs2 + sr * 132))[sk] = srcf4[sk];
        }
        __syncthreads();

        if (isMain) {
            GI_CHUNK(0)
            GI_CHUNK(4)
            GI_CHUNK(8)
            GI_CHUNK(12)
        } else {
            #pragma unroll
            for (int rr = 0; rr < 16; ++rr) {
                float aA = 0.f, aB = 0.f, aC = 0.f;
                GI_ROW(rr, aA, aB, aC)
                RED(aA) RED(aB) RED(aC)
                if (rr == rsp && kq == 0) {
                    GIb[rr * 389 + 128] = aA;
                    GIb[rr * 389 + 257] = aB;
                    GIb[rr * 389 + 386] = aC;
                }
            }
        }
        __syncthreads();

        {
            float* gout = gic + (size_t)tt * 387 * 4096 + b0;
            for (int e = tid; e < 6192; e += 576) {
                int r = e & 15;
                int j = e >> 4;
                gout[(size_t)j * 4096 + r] = GIb[r * 389 + j];
            }
        }
        __syncthreads();
    }
}

// ---------------------------------------------------------------------------
// GRU recurrence v4: weight-resident named scalars + asm-pin + waves_per_eu(3,3).
// ---------------------------------------------------------------------------
#define GH_ROW(R, aA, aB, aC) { \
    const float4* hv_ = (const float4*)(hs2 + (R) * 148) + kqo; \
    float4 h4_; \
    h4_ = hv_[0]; D4(aA, h4_, Wa0) D4(aB, h4_, Wb0) D4(aC, h4_, Wc0) \
    h4_ = hv_[1]; D4(aA, h4_, Wa1) D4(aB, h4_, Wb1) D4(aC, h4_, Wc1) \
    h4_ = hv_[2]; D4(aA, h4_, Wa2) D4(aB, h4_, Wb2) D4(aC, h4_, Wc2) \
    h4_ = hv_[3]; D4(aA, h4_, Wa3) D4(aB, h4_, Wb3) D4(aC, h4_, Wc3) \
    h4_ = hv_[4]; D4(aA, h4_, Wa4) D4(aB, h4_, Wb4) D4(aC, h4_, Wc4) \
    h4_ = hv_[5]; D4(aA, h4_, Wa5) D4(aB, h4_, Wb5) D4(aC, h4_, Wc5) \
    h4_ = hv_[6]; D4(aA, h4_, Wa6) D4(aB, h4_, Wb6) D4(aC, h4_, Wc6) \
    h4_ = hv_[7]; D4(aA, h4_, Wa7) D4(aB, h4_, Wb7) D4(aC, h4_, Wc7) \
    h4_ = hv_[8]; D4(aA, h4_, Wa8) D4(aB, h4_, Wb8) D4(aC, h4_, Wc8) }

#define CHUNK(R0) { \
    float aA0 = 0.f, aB0 = 0.f, aC0 = 0.f, aA1 = 0.f, aB1 = 0.f, aC1 = 0.f; \
    float aA2 = 0.f, aB2 = 0.f, aC2 = 0.f, aA3 = 0.f, aB3 = 0.f, aC3 = 0.f; \
    GH_ROW((R0) + 0, aA0, aB0, aC0) \
    GH_ROW((R0) + 1, aA1, aB1, aC1) \
    GH_ROW((R0) + 2, aA2, aB2, aC2) \
    GH_ROW((R0) + 3, aA3, aB3, aC3) \
    RED(aA0) RED(aB0) RED(aC0) RED(aA1) RED(aB1) RED(aC1) \
    RED(aA2) RED(aB2) RED(aC2) RED(aA3) RED(aB3) RED(aC3) \
    float sA = (kq == 0) ? aA0 : (kq == 1) ? aA1 : (kq == 2) ? aA2 : aA3; \
    float sB = (kq == 0) ? aB0 : (kq == 1) ? aB1 : (kq == 2) ? aB2 : aB3; \
    float sC = (kq == 0) ? aC0 : (kq == 1) ? aC1 : (kq == 2) ? aC2 : aC3; \
    int rw_ = (R0) + kq; \
    GHb[rw_ * 388 + gq]       = sA; \
    GHb[rw_ * 388 + 129 + gq] = sB; \
    GHb[rw_ * 388 + 258 + gq] = sC; }

#define APPLY(E, PGA, PGB, PGC) { \
    int r_ = (E) & 15, j_ = (E) >> 4; \
    float pr_  = (PGA) + GHb[r_ * 388 + j_]       + bihS[j_]       + bhhS[j_]; \
    float pz_  = (PGB) + GHb[r_ * 388 + 129 + j_] + bihS[129 + j_] + bhhS[129 + j_]; \
    float gin_ = (PGC) + bihS[258 + j_]; \
    float ghn_ = GHb[r_ * 388 + 258 + j_] + bhhS[258 + j_]; \
    float rg_ = fast_sigmoid(pr_); \
    float zg_ = fast_sigmoid(pz_); \
    float nn_ = fast_tanh(gin_ + rg_ * ghn_); \
    hs2[r_ * 148 + j_] = (1.f - zg_) * nn_ + zg_ * hs2[r_ * 148 + j_]; }

__global__ __launch_bounds__(576, 3)
__attribute__((amdgpu_waves_per_eu(3, 3)))
void gru_rec(
    const float* __restrict__ gic, const float* __restrict__ whh,  // [387][144]
    const float* __restrict__ bih, const float* __restrict__ bhh,
    float* __restrict__ hstate, float* __restrict__ g_out,
    int t0, int nt)
{
    __shared__ __attribute__((aligned(16))) float hs2[16 * 148];  // stride 148
    __shared__ float GHb[16 * 388];
    __shared__ float bihS[387];
    __shared__ float bhhS[387];

    const int tid    = threadIdx.x;
    const int kq     = tid & 3;
    const int kqo    = kq * 9;           // f4 offset into a 36-float k-chunk
    const int b0     = blockIdx.x * 16;
    const bool isMain = (tid < 512);
    const int gq     = isMain ? (tid >> 2) : 0;      // [0,128)
    const int rsp    = (tid - 512) >> 2;             // special wave batch row

    const float* wrA;
    const float* wrB;
    const float* wrC;
    if (isMain) {
        wrA = whh + (size_t)gq * 144 + kq * 36;
        wrB = whh + (size_t)(129 + gq) * 144 + kq * 36;
        wrC = whh + (size_t)(258 + gq) * 144 + kq * 36;
    } else {
        wrA = whh + (size_t)128 * 144 + kq * 36;
        wrB = whh + (size_t)257 * 144 + kq * 36;
        wrC = whh + (size_t)386 * 144 + kq * 36;
    }
    float4 Wa0 = ((const float4*)wrA)[0], Wa1 = ((const float4*)wrA)[1],
           Wa2 = ((const float4*)wrA)[2], Wa3 = ((const float4*)wrA)[3],
           Wa4 = ((const float4*)wrA)[4], Wa5 = ((const float4*)wrA)[5],
           Wa6 = ((const float4*)wrA)[6], Wa7 = ((const float4*)wrA)[7],
           Wa8 = ((const float4*)wrA)[8];
    float4 Wb0 = ((const float4*)wrB)[0], Wb1 = ((const float4*)wrB)[1],
           Wb2 = ((const float4*)wrB)[2], Wb3 = ((const float4*)wrB)[3],
           Wb4 = ((const float4*)wrB)[4], Wb5 = ((const float4*)wrB)[5],
           Wb6 = ((const float4*)wrB)[6], Wb7 = ((const float4*)wrB)[7],
           Wb8 = ((const float4*)wrB)[8];
    float4 Wc0 = ((const float4*)wrC)[0], Wc1 = ((const float4*)wrC)[1],
           Wc2 = ((const float4*)wrC)[2], Wc3 = ((const float4*)wrC)[3],
           Wc4 = ((const float4*)wrC)[4], Wc5 = ((const float4*)wrC)[5],
           Wc6 = ((const float4*)wrC)[6], Wc7 = ((const float4*)wrC)[7],
           Wc8 = ((const float4*)wrC)[8];
    PIN4(Wa0) PIN4(Wa1) PIN4(Wa2) PIN4(Wa3) PIN4(Wa4) PIN4(Wa5) PIN4(Wa6) PIN4(Wa7) PIN4(Wa8)
    PIN4(Wb0) PIN4(Wb1) PIN4(Wb2) PIN4(Wb3) PIN4(Wb4) PIN4(Wb5) PIN4(Wb6) PIN4(Wb7) PIN4(Wb8)
    PIN4(Wc0) PIN4(Wc1) PIN4(Wc2) PIN4(Wc3) PIN4(Wc4) PIN4(Wc5) PIN4(Wc6) PIN4(Wc7) PIN4(Wc8)

    if (tid < 387) { bihS[tid] = bih[tid]; bhhS[tid] = bhh[tid]; }
    if (t0 == 0) {
        for (int e = tid; e < 16 * 148; e += 576) hs2[e] = 0.f;
    } else {
        for (int e = tid; e < 16 * 148; e += 576) hs2[e] = hstate[(size_t)b0 * 148 + e];
    }
    __syncthreads();

    const int e0 = tid, e1 = tid + 576, e2 = tid + 1152, e3 = tid + 1728;

    for (int tt = 0; tt < nt; ++tt) {
        const float* gib = gic + (size_t)tt * 387 * 4096 + b0;
        float pa0, pb0, pc0, pa1, pb1, pc1, pa2, pb2, pc2;
        float pa3 = 0.f, pb3 = 0.f, pc3 = 0.f;
        {
            int r = e0 & 15, j = e0 >> 4;
            pa0 = gib[(size_t)j * 4096 + r];
            pb0 = gib[(size_t)(129 + j) * 4096 + r];
            pc0 = gib[(size_t)(258 + j) * 4096 + r];
            r = e1 & 15; j = e1 >> 4;
            pa1 = gib[(size_t)j * 4096 + r];
            pb1 = gib[(size_t)(129 + j) * 4096 + r];
            pc1 = gib[(size_t)(258 + j) * 4096 + r];
            r = e2 & 15; j = e2 >> 4;
            pa2 = gib[(size_t)j * 4096 + r];
            pb2 = gib[(size_t)(129 + j) * 4096 + r];
            pc2 = gib[(size_t)(258 + j) * 4096 + r];
            if (e3 < 2064) {
                r = e3 & 15; j = e3 >> 4;
                pa3 = gib[(size_t)j * 4096 + r];
                pb3 = gib[(size_t)(129 + j) * 4096 + r];
                pc3 = gib[(size_t)(258 + j) * 4096 + r];
            }
        }

        if (isMain) {
            CHUNK(0)
            CHUNK(4)
            CHUNK(8)
            CHUNK(12)
        } else {
            float aA = 0.f, aB = 0.f, aC = 0.f;
            GH_ROW(rsp, aA, aB, aC)
            RED(aA) RED(aB) RED(aC)
            if (kq == 0) {
                GHb[rsp * 388 + 128] = aA;
                GHb[rsp * 388 + 257] = aB;
                GHb[rsp * 388 + 386] = aC;
            }
        }
        __syncthreads();

        APPLY(e0, pa0, pb0, pc0)
        APPLY(e1, pa1, pb1, pc1)
        APPLY(e2, pa2, pb2, pc2)
        if (e3 < 2064) { APPLY(e3, pa3, pb3, pc3) }
        __syncthreads();
    }

    for (int e = tid; e < 16 * 148; e += 576) hstate[(size_t)b0 * 148 + e] = hs2[e];
    if (t0 + nt >= 60) {
        if (e0 < 2064) { int r = e0 & 15, j = e0 >> 4; float v = hs2[r * 148 + j];
            g_out[(size_t)(b0 + r) * 129 + j] = (v >= 0.f) ? v : 0.01f * v; }
        if (e1 < 2064) { int r = e1 & 15, j = e1 >> 4; float v = hs2[r * 148 + j];
            g_out[(size_t)(b0 + r) * 129 + j] = (v >= 0.f) ? v : 0.01f * v; }
        if (e2 < 2064) { int r = e2 & 15, j = e2 >> 4; float v = hs2[r * 148 + j];
            g_out[(size_t)(b0 + r) * 129 + j] = (v >= 0.f) ? v : 0.01f * v; }
        if (e3 < 2064) { int r = e3 & 15, j = e3 >> 4; float v = hs2[r * 148 + j];
            g_out[(size_t)(b0 + r) * 129 + j] = (v >= 0.f) ? v : 0.01f * v; }
    }
}

// ---------------------------------------------------------------------------
// Head: feat=[g,w] (258) -> mu, log_std -> sample, tanh, log_pi, normalize.
// ---------------------------------------------------------------------------
__global__ __launch_bounds__(256) void head_kernel(
    const float* __restrict__ gbuf, const float* __restrict__ wvec,
    const float* __restrict__ eps,
    const float* __restrict__ muwp, const float* __restrict__ lswp,
    const float* __restrict__ mub,  const float* __restrict__ lsb,
    float* __restrict__ out)
{
    __shared__ __attribute__((aligned(16))) float feat[16 * 260];
    __shared__ float PA[16 * 130];
    __shared__ float TERM[16 * 130];
    __shared__ float ROWSUM[16];
    __shared__ float ROWLOG[16];

    const int tid = threadIdx.x;
    const int b0  = blockIdx.x * 16;

    for (int i = tid; i < 16 * 260; i += 256) {
        int r = i / 260;
        int k = i - r * 260;
        float v = 0.f;
        if (k < 129)       v = gbuf[(size_t)(b0 + r) * 129 + k];
        else if (k < 258)  v = wvec[(size_t)(b0 + r) * 129 + (k - 129)];
        feat[i] = v;
    }
    __syncthreads();

    for (int idx = tid; idx < 16 * 129; idx += 256) {
        int r = idx & 15;
        int j = idx >> 4;
        const float4* fv = (const float4*)(feat + r * 260);
        const float4* mw = (const float4*)(muwp + (size_t)j * 260);
        const float4* lw = (const float4*)(lswp + (size_t)j * 260);
        float am = 0.f, al = 0.f;
        for (int k = 0; k < 65; ++k) {
            float4 f = fv[k];
            float4 m = mw[k];
            float4 l = lw[k];
            am += f.x * m.x + f.y * m.y + f.z * m.z + f.w * m.w;
            al += f.x * l.x + f.y * l.y + f.z * l.z + f.w * l.w;
        }
        float mu = am + mub[j];
        float ls = fminf(fmaxf(al + lsb[j], -20.f), 2.f);
        float sd = __expf(ls);
        float e  = eps[(size_t)(b0 + r) * 129 + j];
        float xv = mu + sd * e;
        float pa = fast_tanh(xv);
        float tt = (xv - mu) / sd;
        float term = -0.5f * tt * tt - ls - 0.91893853320467274f
                     - __logf(1.f - pa * pa + 1e-6f);
        PA[r * 130 + j]   = pa;
        TERM[r * 130 + j] = term;
    }
    __syncthreads();

    {
        int r = tid >> 4;
        int i = tid & 15;
        float sp = 0.f, st = 0.f;
        for (int j = i; j < 129; j += 16) {
            sp += PA[r * 130 + j];
            st += TERM[r * 130 + j];
        }
        for (int off = 8; off > 0; off >>= 1) {
            sp += __shfl_down(sp, off, 16);
            st += __shfl_down(st, off, 16);
        }
        if (i == 0) { ROWSUM[r] = sp + 129.f; ROWLOG[r] = st; }
    }
    __syncthreads();

    for (int idx = tid; idx < 16 * 129; idx += 256) {
        int r = idx & 15;
        int j = idx >> 4;
        out[(size_t)(b0 + r) * 129 + j] = (PA[r * 130 + j] + 1.f) / ROWSUM[r];
    }
    if (tid < 16)
        out[(size_t)4096 * 129 + b0 + tid] = ROWLOG[tid];
}

// ---------------------------------------------------------------------------
extern "C" void kernel_launch(void* const* d_in, const int* in_sizes, int n_in,
                              void* d_out, int out_size, void* d_ws, size_t ws_size,
                              hipStream_t stream)
{
    const float* x   = (const float*)d_in[0];
    const float* wv  = (const float*)d_in[1];
    const float* eps = (const float*)d_in[2];
    const float* c1w = (const float*)d_in[3];
    const float* c1b = (const float*)d_in[4];
    const float* c2w = (const float*)d_in[5];
    const float* c2b = (const float*)d_in[6];
    const float* Wih = (const float*)d_in[7];
    const float* Whh = (const float*)d_in[8];
    const float* bih = (const float*)d_in[9];
    const float* bhh = (const float*)d_in[10];
    const float* muw = (const float*)d_in[11];
    const float* mub = (const float*)d_in[12];
    const float* lsw = (const float*)d_in[13];
    const float* lsb = (const float*)d_in[14];

    float* ws     = (float*)d_ws;
    float* seq    = ws + SEQ_OFF;
    float* g      = ws + G_OFF;
    float* hstate = ws + HST_OFF;
    float* whh144 = ws + WHH144_OFF;
    float* wih128 = ws + WIH128_OFF;
    float* muwp   = ws + MUWP_OFF;
    float* lswp   = ws + LSWP_OFF;
    float* gic    = ws + GIC_OFF;
    float* outp   = (float*)d_out;

    // chunk size over t, limited by workspace (deterministic given ws_size)
    const long per_t = 387L * 4096;
    long avail = (long)(ws_size / 4) - (long)GIC_OFF;
    int CT = 60;
    if (avail < 60 * per_t) {
        CT = (int)(avail / per_t);
        if (CT < 1) CT = 1;
        if (CT > 60) CT = 60;
    }

    const int prep_elems = 387 * 144 + 387 * 128 + 2 * (129 * 260);
    prep_pad<<<(prep_elems + 255) / 256, 256, 0, stream>>>(Whh, Wih, muw, lsw, ws);
    conv_fused<<<dim3(6, BTOT), 256, 0, stream>>>(x, c1w, c1b, c2w, c2b, seq);

    for (int t0 = 0; t0 < 60; t0 += CT) {
        int nt = 60 - t0; if (nt > CT) nt = CT;
        gi_gemm2<<<256, 576, 0, stream>>>(seq, wih128, gic, t0, nt);
        gru_rec<<<256, 576, 0, stream>>>(gic, whh144, bih, bhh, hstate, g, t0, nt);
    }
    head_kernel<<<BTOT / 16, 256, 0, stream>>>(g, wv, eps, muwp, lswp, mub, lsb, outp);
}

// Round 15
// 2142.437 us; speedup vs baseline: 1.0181x; 1.0181x over previous
//
#include <hip/hip_runtime.h>
#include <math.h>

// Problem constants
#define BTOT   4096
#define CIN    3
#define TIN    64
#define SIN    128

// ws layout (float offsets)
#define SEQ_OFF    0                            // [4096][60][124]
#define G_OFF      (SEQ_OFF + 4096*60*124)      // [4096][129]
#define HST_OFF    (G_OFF + 4096*129)           // [4096][148] h state between chunks
#define WHR_OFF    (HST_OFF + 4096*148)         // [27][576][4] lane-linear Whh
#define WIR_OFF    (WHR_OFF + 27*576*4)         // [24][576][4] lane-linear Wih
#define MUWP_OFF   (WIR_OFF + 24*576*4)         // [129][260]
#define LSWP_OFF   (MUWP_OFF + 129*260)         // [129][260]
#define GIC_OFF    (LSWP_OFF + 129*260)         // [CT][387][4096] gi chunk

// Inline transcendentals (no libm calls in hot loops; ocml calls force
// loop-resident values into callee-saved regs -> spill)
__device__ __forceinline__ float fast_tanh(float x) {
    float ax = fabsf(x);
    float t  = __expf(-2.f * ax);
    float r  = (1.f - t) / (1.f + t);
    return copysignf(r, x);
}
__device__ __forceinline__ float fast_sigmoid(float x) {
    return 1.f / (1.f + __expf(-x));
}

// ---------------------------------------------------------------------------
// Prep: build LANE-LINEAR weight tables (R14 lesson: the allocator reloads
// weights every step no matter what; make each reload a fully-coalesced
// dwordx4 from an L2-resident table instead of a 40-line scattered read).
// whr[m][l][c]: m = g*9+i (g=gate 0..2, i=f4 idx 0..8), l = tid (0..575),
//   thread l: gq = (l<512)? l>>2 : 128, kq = l&3; row = g*129+gq;
//   col = kq*36 + i*4 + c  (0 if col>=129).
// wir[m][l][c]: m = g*8+i; col = kq*32 + i*4 + c (0 if col>=124).
// Plus fc weight padding 258->260.
// ---------------------------------------------------------------------------
__global__ __launch_bounds__(256) void prep_pad(
    const float* __restrict__ Whh, const float* __restrict__ Wih,
    const float* __restrict__ muw, const float* __restrict__ lsw,
    float* __restrict__ ws)
{
    int idx = blockIdx.x * 256 + threadIdx.x;
    const int NH = 27 * 576 * 4;
    const int NI = 24 * 576 * 4;
    const int N2 = 129 * 260;
    if (idx < NH) {
        int m   = idx / 2304;
        int rem = idx - m * 2304;
        int l   = rem >> 2;
        int c   = rem & 3;
        int g   = m / 9;
        int i   = m - g * 9;
        int gq  = (l < 512) ? (l >> 2) : 128;
        int kq  = l & 3;
        int row = g * 129 + gq;
        int col = kq * 36 + i * 4 + c;
        ws[WHR_OFF + idx] = (col < 129) ? Whh[(size_t)row * 129 + col] : 0.f;
    } else if (idx < NH + NI) {
        int i2  = idx - NH;
        int m   = i2 / 2304;
        int rem = i2 - m * 2304;
        int l   = rem >> 2;
        int c   = rem & 3;
        int g   = m / 8;
        int i   = m - g * 8;
        int gq  = (l < 512) ? (l >> 2) : 128;
        int kq  = l & 3;
        int row = g * 129 + gq;
        int col = kq * 32 + i * 4 + c;
        ws[WIR_OFF + i2] = (col < 124) ? Wih[(size_t)row * 124 + col] : 0.f;
    } else if (idx < NH + NI + N2) {
        int i = idx - NH - NI; int j = i / 260, k = i - j * 260;
        ws[MUWP_OFF + i] = (k < 258) ? muw[j * 258 + k] : 0.f;
    } else if (idx < NH + NI + 2 * N2) {
        int i = idx - NH - NI - N2; int j = i / 260, k = i - j * 260;
        ws[LSWP_OFF + i] = (k < 258) ? lsw[j * 258 + k] : 0.f;
    }
}

// ---------------------------------------------------------------------------
// Fused conv1+conv2 v2 (register-blocked, weight-resident) — passing R13.
// ---------------------------------------------------------------------------
#define C1SEG(c_, kt_, W0_, W1_, W2_) { \
    const float* rp_ = xt + ((c_) * 14 + tq + (kt_)) * 128 + s0; \
    float4 v4_ = *(const float4*)rp_; \
    float2 v2_ = *(const float2*)(rp_ + 4); \
    acc0 += v4_.x*(W0_) + v4_.y*(W1_) + v4_.z*(W2_); \
    acc1 += v4_.y*(W0_) + v4_.z*(W1_) + v4_.w*(W2_); \
    acc2 += v4_.z*(W0_) + v4_.w*(W1_) + v2_.x*(W2_); \
    acc3 += v4_.w*(W0_) + v2_.x*(W1_) + v2_.y*(W2_); }

#define C2SEG(o_, kt_, W0_, W1_, W2_) { \
    const float* rp_ = h1t + ((o_) * 12 + tq + (kt_)) * 128 + s0; \
    float4 v4_ = *(const float4*)rp_; \
    float2 v2_ = *(const float2*)(rp_ + 4); \
    acc0 += v4_.x*(W0_) + v4_.y*(W1_) + v4_.z*(W2_); \
    acc1 += v4_.y*(W0_) + v4_.z*(W1_) + v4_.w*(W2_); \
    acc2 += v4_.z*(W0_) + v4_.w*(W1_) + v2_.x*(W2_); \
    acc3 += v4_.w*(W0_) + v2_.x*(W1_) + v2_.y*(W2_); }

__global__ __launch_bounds__(256) void conv_fused(
    const float* __restrict__ x,
    const float* __restrict__ w1, const float* __restrict__ b1,
    const float* __restrict__ w2, const float* __restrict__ b2,
    float* __restrict__ seq)
{
    __shared__ __attribute__((aligned(16))) float xt[3 * 14 * 128 + 8];
    __shared__ __attribute__((aligned(16))) float h1t[6 * 12 * 128];
    __shared__ float w1s[162];
    __shared__ float w2s[54];
    __shared__ float b1s[6];
    __shared__ float b2s;

    const int tid  = threadIdx.x;
    const int tile = blockIdx.x;   // 0..5
    const int bb   = blockIdx.y;   // batch
    const int T0   = tile * 10;

    if (tid < 162)                  w1s[tid] = w1[tid];
    if (tid >= 192 && tid < 246)    w2s[tid - 192] = w2[tid - 192];
    if (tid >= 248 && tid < 254)    b1s[tid - 248] = b1[tid - 248];
    if (tid == 255)                 b2s = b2[0];

    // stage x tile: 42 rows x 32 float4 (coalesced)
    {
        const float* xb = x + (size_t)bb * CIN * TIN * SIN;
        for (int i = tid; i < 3 * 14 * 32; i += 256) {
            int c   = i / (14 * 32);
            int rem = i - c * (14 * 32);
            int t   = rem >> 5;
            int k4  = rem & 31;
            ((float4*)(xt + (c * 14 + t) * 128))[k4] =
                *(const float4*)(xb + ((size_t)(c * TIN + T0 + t)) * SIN + k4 * 4);
        }
    }
    __syncthreads();

    // ---- conv1 + leaky: tid<192, thread = (o, 4-col group), 12 t-rows ----
    if (tid < 192) {
        const int o  = tid >> 5;
        const int s0 = (tid & 31) * 4;
        const float* wb = w1s + o * 27;
        float w000 = wb[0],  w001 = wb[1],  w002 = wb[2];
        float w010 = wb[3],  w011 = wb[4],  w012 = wb[5];
        float w020 = wb[6],  w021 = wb[7],  w022 = wb[8];
        float w100 = wb[9],  w101 = wb[10], w102 = wb[11];
        float w110 = wb[12], w111 = wb[13], w112 = wb[14];
        float w120 = wb[15], w121 = wb[16], w122 = wb[17];
        float w200 = wb[18], w201 = wb[19], w202 = wb[20];
        float w210 = wb[21], w211 = wb[22], w212 = wb[23];
        float w220 = wb[24], w221 = wb[25], w222 = wb[26];
        float bo = b1s[o];
        for (int tq = 0; tq < 12; ++tq) {
            float acc0 = bo, acc1 = bo, acc2 = bo, acc3 = bo;
            C1SEG(0, 0, w000, w001, w002)
            C1SEG(0, 1, w010, w011, w012)
            C1SEG(0, 2, w020, w021, w022)
            C1SEG(1, 0, w100, w101, w102)
            C1SEG(1, 1, w110, w111, w112)
            C1SEG(1, 2, w120, w121, w122)
            C1SEG(2, 0, w200, w201, w202)
            C1SEG(2, 1, w210, w211, w212)
            C1SEG(2, 2, w220, w221, w222)
            float4 r;
            r.x = (acc0 >= 0.f) ? acc0 : 0.01f * acc0;
            r.y = (acc1 >= 0.f) ? acc1 : 0.01f * acc1;
            r.z = (acc2 >= 0.f) ? acc2 : 0.01f * acc2;
            r.w = (acc3 >= 0.f) ? acc3 : 0.01f * acc3;
            *(float4*)(h1t + (o * 12 + tq) * 128 + s0) = r;
        }
    }
    __syncthreads();

    // ---- conv2 + leaky: 310 tasks = (t in [0,10), sg in [0,31)) ----
    {
        float u000 = w2s[0],  u001 = w2s[1],  u002 = w2s[2];
        float u010 = w2s[3],  u011 = w2s[4],  u012 = w2s[5];
        float u020 = w2s[6],  u021 = w2s[7],  u022 = w2s[8];
        float u100 = w2s[9],  u101 = w2s[10], u102 = w2s[11];
        float u110 = w2s[12], u111 = w2s[13], u112 = w2s[14];
        float u120 = w2s[15], u121 = w2s[16], u122 = w2s[17];
        float u200 = w2s[18], u201 = w2s[19], u202 = w2s[20];
        float u210 = w2s[21], u211 = w2s[22], u212 = w2s[23];
        float u220 = w2s[24], u221 = w2s[25], u222 = w2s[26];
        float u300 = w2s[27], u301 = w2s[28], u302 = w2s[29];
        float u310 = w2s[30], u311 = w2s[31], u312 = w2s[32];
        float u320 = w2s[33], u321 = w2s[34], u322 = w2s[35];
        float u400 = w2s[36], u401 = w2s[37], u402 = w2s[38];
        float u410 = w2s[39], u411 = w2s[40], u412 = w2s[41];
        float u420 = w2s[42], u421 = w2s[43], u422 = w2s[44];
        float u500 = w2s[45], u501 = w2s[46], u502 = w2s[47];
        float u510 = w2s[48], u511 = w2s[49], u512 = w2s[50];
        float u520 = w2s[51], u521 = w2s[52], u522 = w2s[53];
        float bo2 = b2s;
        for (int idx = tid; idx < 310; idx += 256) {
            const int tq = idx / 31;
            const int s0 = (idx - tq * 31) * 4;
            float acc0 = bo2, acc1 = bo2, acc2 = bo2, acc3 = bo2;
            C2SEG(0, 0, u000, u001, u002)
            C2SEG(0, 1, u010, u011, u012)
            C2SEG(0, 2, u020, u021, u022)
            C2SEG(1, 0, u100, u101, u102)
            C2SEG(1, 1, u110, u111, u112)
            C2SEG(1, 2, u120, u121, u122)
            C2SEG(2, 0, u200, u201, u202)
            C2SEG(2, 1, u210, u211, u212)
            C2SEG(2, 2, u220, u221, u222)
            C2SEG(3, 0, u300, u301, u302)
            C2SEG(3, 1, u310, u311, u312)
            C2SEG(3, 2, u320, u321, u322)
            C2SEG(4, 0, u400, u401, u402)
            C2SEG(4, 1, u410, u411, u412)
            C2SEG(4, 2, u420, u421, u422)
            C2SEG(5, 0, u500, u501, u502)
            C2SEG(5, 1, u510, u511, u512)
            C2SEG(5, 2, u520, u521, u522)
            float4 r;
            r.x = (acc0 >= 0.f) ? acc0 : 0.01f * acc0;
            r.y = (acc1 >= 0.f) ? acc1 : 0.01f * acc1;
            r.z = (acc2 >= 0.f) ? acc2 : 0.01f * acc2;
            r.w = (acc3 >= 0.f) ? acc3 : 0.01f * acc3;
            *(float4*)(seq + ((size_t)bb * 60 + T0 + tq) * 124 + s0) = r;
        }
    }
}

// ---------------------------------------------------------------------------
// Shared macro kit (R10 lesson: macro params must not be named x/y/z/w)
// ---------------------------------------------------------------------------
#define D4(acc_, hv4_, wv4_) acc_ += (hv4_).x*(wv4_).x + (hv4_).y*(wv4_).y + (hv4_).z*(wv4_).z + (hv4_).w*(wv4_).w;
#define RED(acc_) { acc_ += __shfl_xor(acc_, 1, 64); acc_ += __shfl_xor(acc_, 2, 64); }

// ---------------------------------------------------------------------------
// gi GEMM v3 (lane-linear weight table): 256 blocks x 576 threads.
// Weight f4 #(g,i) for thread tid at wir4[(g*8+i)*576 + tid] — coalesced.
// ---------------------------------------------------------------------------
#define GI_ROW(R, aA, aB, aC) { \
    const float4* hv_ = (const float4*)(xs2 + (R) * 132) + kqo8; \
    float4 h4_; \
    h4_ = hv_[0]; D4(aA, h4_, Va0) D4(aB, h4_, Vb0) D4(aC, h4_, Vc0) \
    h4_ = hv_[1]; D4(aA, h4_, Va1) D4(aB, h4_, Vb1) D4(aC, h4_, Vc1) \
    h4_ = hv_[2]; D4(aA, h4_, Va2) D4(aB, h4_, Vb2) D4(aC, h4_, Vc2) \
    h4_ = hv_[3]; D4(aA, h4_, Va3) D4(aB, h4_, Vb3) D4(aC, h4_, Vc3) \
    h4_ = hv_[4]; D4(aA, h4_, Va4) D4(aB, h4_, Vb4) D4(aC, h4_, Vc4) \
    h4_ = hv_[5]; D4(aA, h4_, Va5) D4(aB, h4_, Vb5) D4(aC, h4_, Vc5) \
    h4_ = hv_[6]; D4(aA, h4_, Va6) D4(aB, h4_, Vb6) D4(aC, h4_, Vc6) \
    h4_ = hv_[7]; D4(aA, h4_, Va7) D4(aB, h4_, Vb7) D4(aC, h4_, Vc7) }

#define GI_CHUNK(R0) { \
    float aA0 = 0.f, aB0 = 0.f, aC0 = 0.f, aA1 = 0.f, aB1 = 0.f, aC1 = 0.f; \
    float aA2 = 0.f, aB2 = 0.f, aC2 = 0.f, aA3 = 0.f, aB3 = 0.f, aC3 = 0.f; \
    GI_ROW((R0) + 0, aA0, aB0, aC0) \
    GI_ROW((R0) + 1, aA1, aB1, aC1) \
    GI_ROW((R0) + 2, aA2, aB2, aC2) \
    GI_ROW((R0) + 3, aA3, aB3, aC3) \
    RED(aA0) RED(aB0) RED(aC0) RED(aA1) RED(aB1) RED(aC1) \
    RED(aA2) RED(aB2) RED(aC2) RED(aA3) RED(aB3) RED(aC3) \
    float sA = (kq == 0) ? aA0 : (kq == 1) ? aA1 : (kq == 2) ? aA2 : aA3; \
    float sB = (kq == 0) ? aB0 : (kq == 1) ? aB1 : (kq == 2) ? aB2 : aB3; \
    float sC = (kq == 0) ? aC0 : (kq == 1) ? aC1 : (kq == 2) ? aC2 : aC3; \
    int rw_ = (R0) + kq; \
    GIb[rw_ * 389 + gq]       = sA; \
    GIb[rw_ * 389 + 129 + gq] = sB; \
    GIb[rw_ * 389 + 258 + gq] = sC; }

__global__ __launch_bounds__(576, 3)
void gi_gemm2(
    const float* __restrict__ seq, const float* __restrict__ wir,  // [24][576][4]
    float* __restrict__ gic, int t0, int nt)
{
    __shared__ __attribute__((aligned(16))) float xs2[16 * 132];  // stride 132
    __shared__ float GIb[16 * 389];

    const int tid    = threadIdx.x;
    const int kq     = tid & 3;
    const int kqo8   = kq * 8;           // f4 offset into a 32-float k-chunk
    const int b0     = blockIdx.x * 16;
    const bool isMain = (tid < 512);
    const int gq     = isMain ? (tid >> 2) : 0;      // [0,128)
    const int rsp    = (tid - 512) >> 2;             // special wave batch row

    // lane-linear coalesced weight loads (L2-resident table)
    const float4* wir4 = (const float4*)wir;
    float4 Va0 = wir4[0*576+tid],  Va1 = wir4[1*576+tid],
           Va2 = wir4[2*576+tid],  Va3 = wir4[3*576+tid],
           Va4 = wir4[4*576+tid],  Va5 = wir4[5*576+tid],
           Va6 = wir4[6*576+tid],  Va7 = wir4[7*576+tid];
    float4 Vb0 = wir4[8*576+tid],  Vb1 = wir4[9*576+tid],
           Vb2 = wir4[10*576+tid], Vb3 = wir4[11*576+tid],
           Vb4 = wir4[12*576+tid], Vb5 = wir4[13*576+tid],
           Vb6 = wir4[14*576+tid], Vb7 = wir4[15*576+tid];
    float4 Vc0 = wir4[16*576+tid], Vc1 = wir4[17*576+tid],
           Vc2 = wir4[18*576+tid], Vc3 = wir4[19*576+tid],
           Vc4 = wir4[20*576+tid], Vc5 = wir4[21*576+tid],
           Vc6 = wir4[22*576+tid], Vc7 = wir4[23*576+tid];

    // zero the k-pad (floats 124..127 of each row) so 0-weight x pad = 0
    if (tid < 64) xs2[(tid >> 2) * 132 + 124 + (tid & 3)] = 0.f;

    const int sr = tid / 31;             // row 0..15 (tid<496)
    const int sk = tid - sr * 31;        // f4 0..30

    for (int tt = 0; tt < nt; ++tt) {
        if (tid < 496) {
            const float4* srcf4 =
                (const float4*)(seq + ((size_t)(b0 + sr) * 60 + (t0 + tt)) * 124);
            ((float4*)(xs2 + sr * 132))[sk] = srcf4[sk];
        }
        __syncthreads();

        if (isMain) {
            GI_CHUNK(0)
            GI_CHUNK(4)
            GI_CHUNK(8)
            GI_CHUNK(12)
        } else {
            #pragma unroll
            for (int rr = 0; rr < 16; ++rr) {
                float aA = 0.f, aB = 0.f, aC = 0.f;
                GI_ROW(rr, aA, aB, aC)
                RED(aA) RED(aB) RED(aC)
                if (rr == rsp && kq == 0) {
                    GIb[rr * 389 + 128] = aA;
                    GIb[rr * 389 + 257] = aB;
                    GIb[rr * 389 + 386] = aC;
                }
            }
        }
        __syncthreads();

        {
            float* gout = gic + (size_t)tt * 387 * 4096 + b0;
            for (int e = tid; e < 6192; e += 576) {
                int r = e & 15;
                int j = e >> 4;
                gout[(size_t)j * 4096 + r] = GIb[r * 389 + j];
            }
        }
        __syncthreads();
    }
}

// ---------------------------------------------------------------------------
// GRU recurrence v5: lane-linear weight table (coalesced reloads are cheap;
// stop fighting the register allocator — R7/R8/R13/R14 all failed to pin).
// ---------------------------------------------------------------------------
#define GH_ROW(R, aA, aB, aC) { \
    const float4* hv_ = (const float4*)(hs2 + (R) * 148) + kqo; \
    float4 h4_; \
    h4_ = hv_[0]; D4(aA, h4_, Wa0) D4(aB, h4_, Wb0) D4(aC, h4_, Wc0) \
    h4_ = hv_[1]; D4(aA, h4_, Wa1) D4(aB, h4_, Wb1) D4(aC, h4_, Wc1) \
    h4_ = hv_[2]; D4(aA, h4_, Wa2) D4(aB, h4_, Wb2) D4(aC, h4_, Wc2) \
    h4_ = hv_[3]; D4(aA, h4_, Wa3) D4(aB, h4_, Wb3) D4(aC, h4_, Wc3) \
    h4_ = hv_[4]; D4(aA, h4_, Wa4) D4(aB, h4_, Wb4) D4(aC, h4_, Wc4) \
    h4_ = hv_[5]; D4(aA, h4_, Wa5) D4(aB, h4_, Wb5) D4(aC, h4_, Wc5) \
    h4_ = hv_[6]; D4(aA, h4_, Wa6) D4(aB, h4_, Wb6) D4(aC, h4_, Wc6) \
    h4_ = hv_[7]; D4(aA, h4_, Wa7) D4(aB, h4_, Wb7) D4(aC, h4_, Wc7) \
    h4_ = hv_[8]; D4(aA, h4_, Wa8) D4(aB, h4_, Wb8) D4(aC, h4_, Wc8) }

#define CHUNK(R0) { \
    float aA0 = 0.f, aB0 = 0.f, aC0 = 0.f, aA1 = 0.f, aB1 = 0.f, aC1 = 0.f; \
    float aA2 = 0.f, aB2 = 0.f, aC2 = 0.f, aA3 = 0.f, aB3 = 0.f, aC3 = 0.f; \
    GH_ROW((R0) + 0, aA0, aB0, aC0) \
    GH_ROW((R0) + 1, aA1, aB1, aC1) \
    GH_ROW((R0) + 2, aA2, aB2, aC2) \
    GH_ROW((R0) + 3, aA3, aB3, aC3) \
    RED(aA0) RED(aB0) RED(aC0) RED(aA1) RED(aB1) RED(aC1) \
    RED(aA2) RED(aB2) RED(aC2) RED(aA3) RED(aB3) RED(aC3) \
    float sA = (kq == 0) ? aA0 : (kq == 1) ? aA1 : (kq == 2) ? aA2 : aA3; \
    float sB = (kq == 0) ? aB0 : (kq == 1) ? aB1 : (kq == 2) ? aB2 : aB3; \
    float sC = (kq == 0) ? aC0 : (kq == 1) ? aC1 : (kq == 2) ? aC2 : aC3; \
    int rw_ = (R0) + kq; \
    GHb[rw_ * 388 + gq]       = sA; \
    GHb[rw_ * 388 + 129 + gq] = sB; \
    GHb[rw_ * 388 + 258 + gq] = sC; }

#define APPLY(E, PGA, PGB, PGC) { \
    int r_ = (E) & 15, j_ = (E) >> 4; \
    float pr_  = (PGA) + GHb[r_ * 388 + j_]       + bihS[j_]       + bhhS[j_]; \
    float pz_  = (PGB) + GHb[r_ * 388 + 129 + j_] + bihS[129 + j_] + bhhS[129 + j_]; \
    float gin_ = (PGC) + bihS[258 + j_]; \
    float ghn_ = GHb[r_ * 388 + 258 + j_] + bhhS[258 + j_]; \
    float rg_ = fast_sigmoid(pr_); \
    float zg_ = fast_sigmoid(pz_); \
    float nn_ = fast_tanh(gin_ + rg_ * ghn_); \
    hs2[r_ * 148 + j_] = (1.f - zg_) * nn_ + zg_ * hs2[r_ * 148 + j_]; }

__global__ __launch_bounds__(576, 3)
void gru_rec(
    const float* __restrict__ gic, const float* __restrict__ whr,  // [27][576][4]
    const float* __restrict__ bih, const float* __restrict__ bhh,
    float* __restrict__ hstate, float* __restrict__ g_out,
    int t0, int nt)
{
    __shared__ __attribute__((aligned(16))) float hs2[16 * 148];  // stride 148
    __shared__ float GHb[16 * 388];
    __shared__ float bihS[387];
    __shared__ float bhhS[387];

    const int tid    = threadIdx.x;
    const int kq     = tid & 3;
    const int kqo    = kq * 9;           // f4 offset into a 36-float k-chunk
    const int b0     = blockIdx.x * 16;
    const bool isMain = (tid < 512);
    const int gq     = isMain ? (tid >> 2) : 0;      // [0,128)
    const int rsp    = (tid - 512) >> 2;             // special wave batch row

    // lane-linear coalesced weight loads (L2-resident table)
    const float4* whr4 = (const float4*)whr;
    float4 Wa0 = whr4[0*576+tid],  Wa1 = whr4[1*576+tid],
           Wa2 = whr4[2*576+tid],  Wa3 = whr4[3*576+tid],
           Wa4 = whr4[4*576+tid],  Wa5 = whr4[5*576+tid],
           Wa6 = whr4[6*576+tid],  Wa7 = whr4[7*576+tid],
           Wa8 = whr4[8*576+tid];
    float4 Wb0 = whr4[9*576+tid],  Wb1 = whr4[10*576+tid],
           Wb2 = whr4[11*576+tid], Wb3 = whr4[12*576+tid],
           Wb4 = whr4[13*576+tid], Wb5 = whr4[14*576+tid],
           Wb6 = whr4[15*576+tid], Wb7 = whr4[16*576+tid],
           Wb8 = whr4[17*576+tid];
    float4 Wc0 = whr4[18*576+tid], Wc1 = whr4[19*576+tid],
           Wc2 = whr4[20*576+tid], Wc3 = whr4[21*576+tid],
           Wc4 = whr4[22*576+tid], Wc5 = whr4[23*576+tid],
           Wc6 = whr4[24*576+tid], Wc7 = whr4[25*576+tid],
           Wc8 = whr4[26*576+tid];

    if (tid < 387) { bihS[tid] = bih[tid]; bhhS[tid] = bhh[tid]; }
    if (t0 == 0) {
        for (int e = tid; e < 16 * 148; e += 576) hs2[e] = 0.f;
    } else {
        for (int e = tid; e < 16 * 148; e += 576) hs2[e] = hstate[(size_t)b0 * 148 + e];
    }
    __syncthreads();

    const int e0 = tid, e1 = tid + 576, e2 = tid + 1152, e3 = tid + 1728;

    for (int tt = 0; tt < nt; ++tt) {
        const float* gib = gic + (size_t)tt * 387 * 4096 + b0;
        float pa0, pb0, pc0, pa1, pb1, pc1, pa2, pb2, pc2;
        float pa3 = 0.f, pb3 = 0.f, pc3 = 0.f;
        {
            int r = e0 & 15, j = e0 >> 4;
            pa0 = gib[(size_t)j * 4096 + r];
            pb0 = gib[(size_t)(129 + j) * 4096 + r];
            pc0 = gib[(size_t)(258 + j) * 4096 + r];
            r = e1 & 15; j = e1 >> 4;
            pa1 = gib[(size_t)j * 4096 + r];
            pb1 = gib[(size_t)(129 + j) * 4096 + r];
            pc1 = gib[(size_t)(258 + j) * 4096 + r];
            r = e2 & 15; j = e2 >> 4;
            pa2 = gib[(size_t)j * 4096 + r];
            pb2 = gib[(size_t)(129 + j) * 4096 + r];
            pc2 = gib[(size_t)(258 + j) * 4096 + r];
            if (e3 < 2064) {
                r = e3 & 15; j = e3 >> 4;
                pa3 = gib[(size_t)j * 4096 + r];
                pb3 = gib[(size_t)(129 + j) * 4096 + r];
                pc3 = gib[(size_t)(258 + j) * 4096 + r];
            }
        }

        if (isMain) {
            CHUNK(0)
            CHUNK(4)
            CHUNK(8)
            CHUNK(12)
        } else {
            float aA = 0.f, aB = 0.f, aC = 0.f;
            GH_ROW(rsp, aA, aB, aC)
            RED(aA) RED(aB) RED(aC)
            if (kq == 0) {
                GHb[rsp * 388 + 128] = aA;
                GHb[rsp * 388 + 257] = aB;
                GHb[rsp * 388 + 386] = aC;
            }
        }
        __syncthreads();

        APPLY(e0, pa0, pb0, pc0)
        APPLY(e1, pa1, pb1, pc1)
        APPLY(e2, pa2, pb2, pc2)
        if (e3 < 2064) { APPLY(e3, pa3, pb3, pc3) }
        __syncthreads();
    }

    for (int e = tid; e < 16 * 148; e += 576) hstate[(size_t)b0 * 148 + e] = hs2[e];
    if (t0 + nt >= 60) {
        if (e0 < 2064) { int r = e0 & 15, j = e0 >> 4; float v = hs2[r * 148 + j];
            g_out[(size_t)(b0 + r) * 129 + j] = (v >= 0.f) ? v : 0.01f * v; }
        if (e1 < 2064) { int r = e1 & 15, j = e1 >> 4; float v = hs2[r * 148 + j];
            g_out[(size_t)(b0 + r) * 129 + j] = (v >= 0.f) ? v : 0.01f * v; }
        if (e2 < 2064) { int r = e2 & 15, j = e2 >> 4; float v = hs2[r * 148 + j];
            g_out[(size_t)(b0 + r) * 129 + j] = (v >= 0.f) ? v : 0.01f * v; }
        if (e3 < 2064) { int r = e3 & 15, j = e3 >> 4; float v = hs2[r * 148 + j];
            g_out[(size_t)(b0 + r) * 129 + j] = (v >= 0.f) ? v : 0.01f * v; }
    }
}

// ---------------------------------------------------------------------------
// Head: feat=[g,w] (258) -> mu, log_std -> sample, tanh, log_pi, normalize.
// ---------------------------------------------------------------------------
__global__ __launch_bounds__(256) void head_kernel(
    const float* __restrict__ gbuf, const float* __restrict__ wvec,
    const float* __restrict__ eps,
    const float* __restrict__ muwp, const float* __restrict__ lswp,
    const float* __restrict__ mub,  const float* __restrict__ lsb,
    float* __restrict__ out)
{
    __shared__ __attribute__((aligned(16))) float feat[16 * 260];
    __shared__ float PA[16 * 130];
    __shared__ float TERM[16 * 130];
    __shared__ float ROWSUM[16];
    __shared__ float ROWLOG[16];

    const int tid = threadIdx.x;
    const int b0  = blockIdx.x * 16;

    for (int i = tid; i < 16 * 260; i += 256) {
        int r = i / 260;
        int k = i - r * 260;
        float v = 0.f;
        if (k < 129)       v = gbuf[(size_t)(b0 + r) * 129 + k];
        else if (k < 258)  v = wvec[(size_t)(b0 + r) * 129 + (k - 129)];
        feat[i] = v;
    }
    __syncthreads();

    for (int idx = tid; idx < 16 * 129; idx += 256) {
        int r = idx & 15;
        int j = idx >> 4;
        const float4* fv = (const float4*)(feat + r * 260);
        const float4* mw = (const float4*)(muwp + (size_t)j * 260);
        const float4* lw = (const float4*)(lswp + (size_t)j * 260);
        float am = 0.f, al = 0.f;
        for (int k = 0; k < 65; ++k) {
            float4 f = fv[k];
            float4 m = mw[k];
            float4 l = lw[k];
            am += f.x * m.x + f.y * m.y + f.z * m.z + f.w * m.w;
            al += f.x * l.x + f.y * l.y + f.z * l.z + f.w * l.w;
        }
        float mu = am + mub[j];
        float ls = fminf(fmaxf(al + lsb[j], -20.f), 2.f);
        float sd = __expf(ls);
        float e  = eps[(size_t)(b0 + r) * 129 + j];
        float xv = mu + sd * e;
        float pa = fast_tanh(xv);
        float tt = (xv - mu) / sd;
        float term = -0.5f * tt * tt - ls - 0.91893853320467274f
                     - __logf(1.f - pa * pa + 1e-6f);
        PA[r * 130 + j]   = pa;
        TERM[r * 130 + j] = term;
    }
    __syncthreads();

    {
        int r = tid >> 4;
        int i = tid & 15;
        float sp = 0.f, st = 0.f;
        for (int j = i; j < 129; j += 16) {
            sp += PA[r * 130 + j];
            st += TERM[r * 130 + j];
        }
        for (int off = 8; off > 0; off >>= 1) {
            sp += __shfl_down(sp, off, 16);
            st += __shfl_down(st, off, 16);
        }
        if (i == 0) { ROWSUM[r] = sp + 129.f; ROWLOG[r] = st; }
    }
    __syncthreads();

    for (int idx = tid; idx < 16 * 129; idx += 256) {
        int r = idx & 15;
        int j = idx >> 4;
        out[(size_t)(b0 + r) * 129 + j] = (PA[r * 130 + j] + 1.f) / ROWSUM[r];
    }
    if (tid < 16)
        out[(size_t)4096 * 129 + b0 + tid] = ROWLOG[tid];
}

// ---------------------------------------------------------------------------
extern "C" void kernel_launch(void* const* d_in, const int* in_sizes, int n_in,
                              void* d_out, int out_size, void* d_ws, size_t ws_size,
                              hipStream_t stream)
{
    const float* x   = (const float*)d_in[0];
    const float* wv  = (const float*)d_in[1];
    const float* eps = (const float*)d_in[2];
    const float* c1w = (const float*)d_in[3];
    const float* c1b = (const float*)d_in[4];
    const float* c2w = (const float*)d_in[5];
    const float* c2b = (const float*)d_in[6];
    const float* Wih = (const float*)d_in[7];
    const float* Whh = (const float*)d_in[8];
    const float* bih = (const float*)d_in[9];
    const float* bhh = (const float*)d_in[10];
    const float* muw = (const float*)d_in[11];
    const float* mub = (const float*)d_in[12];
    const float* lsw = (const float*)d_in[13];
    const float* lsb = (const float*)d_in[14];

    float* ws     = (float*)d_ws;
    float* seq    = ws + SEQ_OFF;
    float* g      = ws + G_OFF;
    float* hstate = ws + HST_OFF;
    float* whr    = ws + WHR_OFF;
    float* wir    = ws + WIR_OFF;
    float* muwp   = ws + MUWP_OFF;
    float* lswp   = ws + LSWP_OFF;
    float* gic    = ws + GIC_OFF;
    float* outp   = (float*)d_out;

    // chunk size over t, limited by workspace (deterministic given ws_size)
    const long per_t = 387L * 4096;
    long avail = (long)(ws_size / 4) - (long)GIC_OFF;
    int CT = 60;
    if (avail < 60 * per_t) {
        CT = (int)(avail / per_t);
        if (CT < 1) CT = 1;
        if (CT > 60) CT = 60;
    }

    const int prep_elems = 27 * 576 * 4 + 24 * 576 * 4 + 2 * (129 * 260);
    prep_pad<<<(prep_elems + 255) / 256, 256, 0, stream>>>(Whh, Wih, muw, lsw, ws);
    conv_fused<<<dim3(6, BTOT), 256, 0, stream>>>(x, c1w, c1b, c2w, c2b, seq);

    for (int t0 = 0; t0 < 60; t0 += CT) {
        int nt = 60 - t0; if (nt > CT) nt = CT;
        gi_gemm2<<<256, 576, 0, stream>>>(seq, wir, gic, t0, nt);
        gru_rec<<<256, 576, 0, stream>>>(gic, whr, bih, bhh, hstate, g, t0, nt);
    }
    head_kernel<<<BTOT / 16, 256, 0, stream>>>(g, wv, eps, muwp, lswp, mub, lsb, outp);
}